// Round 12
// baseline (457.581 us; speedup 1.0000x reference)
//
#include <hip/hip_runtime.h>
#include <math.h>

#define NNODES 50000
#define NEDGES 800000
#define COUT 64
#define TILE_E 64
#define NTILES (NEDGES / TILE_E)   // 12500, exact
#define GRID 1024                  // 256 CU x 4 blocks
#define KEY_NEG_INF 0x007FFFFFu    // fkey(-inf)
#define NB1 391                    // coarse buckets (dst>>7) == P1 chunks
#define NB1P 392                   // padded stride
#define CHUNK 2048                 // edges per K1 block
#define P2CAP 2816                 // LDS rec capacity per bucket (mean 2048 + 17 sigma)

typedef short bf16x8 __attribute__((ext_vector_type(8)));
typedef float f32x4 __attribute__((ext_vector_type(4)));
#define MFMA16 __builtin_amdgcn_mfma_f32_16x16x32_bf16

// fp32 -> bf16 RTNE
__device__ __forceinline__ unsigned short f2bf(float x) {
    union { float f; unsigned u; } v; v.f = x;
    unsigned r = v.u + 0x7fffu + ((v.u >> 16) & 1u);
    return (unsigned short)(r >> 16);
}

// order-preserving float -> uint key
__device__ __forceinline__ unsigned fkey(float v) {
    unsigned u = __float_as_uint(v);
    return u ^ ((unsigned)((int)u >> 31) | 0x80000000u);
}

// ---------------------------------------------------------------------------
// K1: fused prep (featbf table + out-init) + per-chunk coarse histogram
// ---------------------------------------------------------------------------
__global__ __launch_bounds__(256) void k1_kernel(const float* __restrict__ feat,
                                                 const int* __restrict__ ei,
                                                 unsigned short* __restrict__ featbf,
                                                 unsigned* __restrict__ out,
                                                 unsigned* __restrict__ cnt1) {
    __shared__ unsigned h[NB1];
    const int t = threadIdx.x, blk = blockIdx.x;
    for (int i = t; i < NB1; i += 256) h[i] = 0u;
    __syncthreads();
    const int e0 = blk * CHUNK;
    for (int i = t; i < CHUNK; i += 256) {
        int e = e0 + i;
        if (e < NEDGES) atomicAdd(&h[(unsigned)ei[NEDGES + e] >> 7], 1u);
    }
    // grid-stride fused work (no LDS interaction)
    const int gid = blk * 256 + t, gst = NB1 * 256;
    for (int j = gid; j < (NNODES * COUT) / 8; j += gst) {
        const float4* pp = (const float4*)(feat + (size_t)j * 8);
        float4 x = pp[0], y = pp[1];
        union { unsigned short u[8]; uint4 v; } r;
        r.u[0] = f2bf(x.x); r.u[1] = f2bf(x.y); r.u[2] = f2bf(x.z); r.u[3] = f2bf(x.w);
        r.u[4] = f2bf(y.x); r.u[5] = f2bf(y.y); r.u[6] = f2bf(y.z); r.u[7] = f2bf(y.w);
        ((uint4*)featbf)[j] = r.v;
    }
    const uint4 ninf4 = make_uint4(KEY_NEG_INF, KEY_NEG_INF, KEY_NEG_INF, KEY_NEG_INF);
    for (int j = gid; j < (NNODES * COUT) / 4; j += gst) ((uint4*)out)[j] = ninf4;
    __syncthreads();
    for (int i = t; i < NB1; i += 256) cnt1[blk * NB1P + i] = h[i];
}

// ---------------------------------------------------------------------------
// K2 (1 block): totals = column-sums of cnt1; scan -> base; ticket = base
// ---------------------------------------------------------------------------
__global__ __launch_bounds__(512) void k2_kernel(const unsigned* __restrict__ cnt1,
                                                 unsigned* __restrict__ base,
                                                 unsigned* __restrict__ ticket) {
    __shared__ unsigned sh[512];
    const int t = threadIdx.x;
    unsigned v = 0u;
    if (t < NB1) {
        for (int blk = 0; blk < NB1; ++blk) v += cnt1[blk * NB1P + t];
    }
    sh[t] = v;
    __syncthreads();
    for (int off = 1; off < 512; off <<= 1) {
        unsigned add = (t >= off) ? sh[t - off] : 0u;
        __syncthreads();
        sh[t] += add;
        __syncthreads();
    }
    if (t <= NB1) {
        unsigned excl = sh[t] - v;      // t==NB1: v=0 -> total
        base[t] = excl;
        if (t < NB1) ticket[t] = excl;
    }
}

// ---------------------------------------------------------------------------
// K3: scatter edges into coarse buckets via hot ticket counters (391 lines)
// ---------------------------------------------------------------------------
__global__ void k3_kernel(const int* __restrict__ ei, const int* __restrict__ ea,
                          unsigned* __restrict__ ticket, int2* __restrict__ rec) {
    int i = blockIdx.x * blockDim.x + threadIdx.x;
    int st = gridDim.x * blockDim.x;
    for (int e = i; e < NEDGES; e += st) {
        int d = ei[NEDGES + e];
        unsigned p = atomicAdd(&ticket[(unsigned)d >> 7], 1u);
        rec[p] = make_int2(ei[e] | (ea[e] << 20), d);
    }
}

// ---------------------------------------------------------------------------
// K4: per-bucket full sort by dst (128 bins), in place via LDS buffer
// ---------------------------------------------------------------------------
__global__ __launch_bounds__(512) void p2_kernel(const unsigned* __restrict__ base,
                                                 int2* __restrict__ rec) {
    __shared__ int2 buf[P2CAP];
    __shared__ unsigned hist[128], dbase[128];
    const int t = threadIdx.x, b = blockIdx.x;
    const unsigned lo = base[b];
    int n = (int)(base[b + 1] - lo);
    if (n > P2CAP) n = P2CAP;        // statistically unreachable
    for (int i = t; i < 128; i += 512) hist[i] = 0u;
    __syncthreads();
    for (int i = t; i < n; i += 512) {
        int2 r = rec[lo + i];
        buf[i] = r;
        atomicAdd(&hist[r.y & 127], 1u);
    }
    __syncthreads();
    if (t < 64) {                    // wave 0: scan 128 bins, 2 per lane
        unsigned h0 = hist[2 * t], h1 = hist[2 * t + 1];
        unsigned s = h0 + h1;
        unsigned inc = s;
        #pragma unroll
        for (int off = 1; off < 64; off <<= 1) {
            unsigned nb = __shfl_up(inc, off, 64);
            if (t >= off) inc += nb;
        }
        unsigned excl = inc - s;
        dbase[2 * t] = excl;
        dbase[2 * t + 1] = excl + h0;
    }
    __syncthreads();
    for (int i = t; i < 128; i += 512) hist[i] = 0u;   // reuse as rank counters
    __syncthreads();
    for (int i = t; i < n; i += 512) {
        int2 r = buf[i];
        int ld = r.y & 127;
        unsigned rk = atomicAdd(&hist[ld], 1u);
        rec[lo + dbase[ld] + rk] = r;
    }
}

__global__ void finalize_kernel(float* __restrict__ out, int n) {
    int i = blockIdx.x * blockDim.x + threadIdx.x;
    int stride = gridDim.x * blockDim.x;
    for (; i < n; i += stride) {
        unsigned k = ((unsigned*)out)[i];
        unsigned u = (k & 0x80000000u) ? (k ^ 0x80000000u) : ~k;
        out[i] = (u == 0xFF800000u) ? 0.0f : __uint_as_float(u);
    }
}

// ---------------------------------------------------------------------------
// K5: MFMA edge kernel over dst-sorted records — round-8 version verbatim
// (best measured: 65 µs). K=160 augmented tile, W frags in regs, Kt transpose
// + 16-row segmented flush, 2 barriers/tile, dstv double-buffered.
// ---------------------------------------------------------------------------
__global__ __launch_bounds__(256, 4) void edge_mfma_kernel(
    const unsigned short* __restrict__ featbf, const float* __restrict__ pos,
    const float* __restrict__ W, const float* __restrict__ b,
    const int2* __restrict__ rec, unsigned* __restrict__ out)
{
    __shared__ char SMEM[37376];
    bf16x8*   Amsg = (bf16x8*)SMEM;               // [20][64] 16B units, 20480 B
    unsigned* Kt   = (unsigned*)(SMEM + 20480);   // [4096], 16384 B
    int*      dstv = (int*)(SMEM + 36864);        // [2][64]

    const int tid = threadIdx.x;
    const int lane = tid & 63, w = tid >> 6;
    const int rg = w >> 1, cg = w & 1;
    const int la = lane & 15, lh = lane >> 4;
    const bf16x8 zero8 = {0, 0, 0, 0, 0, 0, 0, 0};

    // ---- stage W_aug [col j][k 0..159] bf16 into SMEM (one-time) ----
    {
        unsigned short* Ws = (unsigned short*)SMEM;   // 64*160*2 = 20480 B
        for (int idx = tid; idx < 160 * 64; idx += 256) {
            int k = idx >> 6, j = idx & 63;           // coalesced over j
            int t = (k >= 80);
            int kk = k - t * 80;
            float v = 0.0f;
            if (kk < 71)       v = W[(t * 71 + kk) * 64 + j];
            else if (kk == 71) v = b[t * 64 + j];
            Ws[j * 160 + k] = f2bf(v);
        }
    }
    __syncthreads();
    bf16x8 wb0[5], wb1[5];
    {
        const bf16x8* Wv = (const bf16x8*)SMEM;       // frag = Wv[col*20 + slot]
        const int c0 = cg * 32 + la, c1 = c0 + 16;
        #pragma unroll
        for (int ks = 0; ks < 5; ++ks) {
            wb0[ks] = Wv[c0 * 20 + ks * 4 + lh];
            wb1[ks] = Wv[c1 * 20 + ks * 4 + lh];
        }
    }
    __syncthreads();                                  // all frags held
    // one-time zero of slots 9 and 19 (never written in the loop)
    if (tid < 128) {
        Amsg[(9 + (tid >> 6) * 10) * 64 + (tid & 63)] = zero8;
    }
    __syncthreads();

    const int row = tid >> 2, c = tid & 3;

    int it = 0;
    for (int tile = blockIdx.x; tile < NTILES; tile += GRID, ++it) {
        const int p = it & 1;
        // ---------------- stage 64 sorted edges ----------------
        const int2 r2 = rec[tile * TILE_E + row];
        const int src = r2.x & 0xFFFFF;
        const int t = r2.x >> 20;
        const int ot = 1 - t;

        const uint4* g = (const uint4*)(featbf + (size_t)src * 64);   // 8x16B
        uint4 q0 = g[2 * c], q1 = g[2 * c + 1];
        *(uint4*)&Amsg[(t * 10 + 2 * c) * 64 + row]     = q0;
        *(uint4*)&Amsg[(t * 10 + 2 * c + 1) * 64 + row] = q1;
        Amsg[(ot * 10 + 2 * c) * 64 + row]     = zero8;
        Amsg[(ot * 10 + 2 * c + 1) * 64 + row] = zero8;

        if (c == 0) {
            int dst = r2.y;
            float ps0 = pos[src * 3], ps1 = pos[src * 3 + 1], ps2 = pos[src * 3 + 2];
            float d0 = pos[dst * 3] - ps0, d1 = pos[dst * 3 + 1] - ps1, d2 = pos[dst * 3 + 2] - ps2;
            float dist = sqrtf(d0 * d0 + d1 * d1 + d2 * d2);
            union { bf16x8 v; unsigned short u[8]; } pt;
            pt.u[0] = f2bf(ps0); pt.u[1] = f2bf(ps1); pt.u[2] = f2bf(ps2);
            pt.u[3] = f2bf(d0);  pt.u[4] = f2bf(d1);  pt.u[5] = f2bf(d2);
            pt.u[6] = f2bf(dist); pt.u[7] = f2bf(1.0f);
            Amsg[(t * 10 + 8) * 64 + row] = pt.v;
        } else if (c == 1) {
            Amsg[(ot * 10 + 8) * 64 + row] = zero8;
        } else if (c == 3) {
            dstv[p * 64 + row] = r2.y;
        }
        __syncthreads();                                   // B1: tile staged

        // ---------------- mfma: 32x32 tile per wave, W from regs ----------------
        f32x4 acc00 = {0,0,0,0}, acc01 = {0,0,0,0}, acc10 = {0,0,0,0}, acc11 = {0,0,0,0};
        const int r0 = rg * 32 + la, r1 = r0 + 16;
        #pragma unroll
        for (int ks = 0; ks < 5; ++ks) {
            bf16x8 a0 = Amsg[(ks * 4 + lh) * 64 + r0];
            bf16x8 a1 = Amsg[(ks * 4 + lh) * 64 + r1];
            acc00 = MFMA16(a0, wb0[ks], acc00, 0, 0, 0);
            acc01 = MFMA16(a0, wb1[ks], acc01, 0, 0, 0);
            acc10 = MFMA16(a1, wb0[ks], acc10, 0, 0, 0);
            acc11 = MFMA16(a1, wb1[ks], acc11, 0, 0, 0);
        }

        // ---------------- keys -> Kt (swizzled, 2-way free) ----------------
        const int col0 = cg * 32 + la, col1 = col0 + 16;
        #pragma unroll
        for (int i = 0; i < 4; ++i) {
            int e0 = rg * 32 + lh * 4 + i, e1 = e0 + 16;
            Kt[e0 * 64 + (col0 ^ ((e0 << 2) & 31))] = fkey(acc00[i]);
            Kt[e0 * 64 + (col1 ^ ((e0 << 2) & 31))] = fkey(acc01[i]);
            Kt[e1 * 64 + (col0 ^ ((e1 << 2) & 31))] = fkey(acc10[i]);
            Kt[e1 * 64 + (col1 ^ ((e1 << 2) & 31))] = fkey(acc11[i]);
        }
        __syncthreads();                                   // B2: keys visible

        // ---- segmented max: thread (col, 16-row quarter), sorted dsts ----
        {
            const int colr = tid & 63;
            const int rbeg = (tid >> 6) * 16;
            unsigned cur = Kt[rbeg * 64 + (colr ^ ((rbeg << 2) & 31))];
            int curd = dstv[p * 64 + rbeg];
            #pragma unroll
            for (int r = rbeg + 1; r < rbeg + 16; ++r) {
                unsigned k = Kt[r * 64 + (colr ^ ((r << 2) & 31))];
                int d = dstv[p * 64 + r];
                if (d != curd) {
                    atomicMax(out + (size_t)curd * COUT + colr, cur);
                    curd = d; cur = k;
                } else {
                    cur = (k > cur) ? k : cur;
                }
            }
            atomicMax(out + (size_t)curd * COUT + colr, cur);
        }
        // next staging: Amsg writes land in slots read before B2; dstv is
        // double-buffered; Kt(n+1) writes are gated by B1(n+1).
    }
}

extern "C" void kernel_launch(void* const* d_in, const int* in_sizes, int n_in,
                              void* d_out, int out_size, void* d_ws, size_t ws_size,
                              hipStream_t stream) {
    const float* feat = (const float*)d_in[0];
    const float* pos  = (const float*)d_in[1];
    const float* W    = (const float*)d_in[2];
    const float* b    = (const float*)d_in[3];
    const int*   ei   = (const int*)d_in[4];
    const int*   ea   = (const int*)d_in[5];
    unsigned* out = (unsigned*)d_out;

    // ws: featbf 6.4MB | rec 6.4MB | cnt1 613KB | base 1.6KB | ticket 1.6KB
    unsigned short* featbf = (unsigned short*)d_ws;
    int2*     rec    = (int2*)((char*)d_ws + (size_t)NNODES * COUT * 2);
    unsigned* cnt1   = (unsigned*)(rec + NEDGES);
    unsigned* base   = cnt1 + NB1 * NB1P;
    unsigned* ticket = base + (NB1 + 1);

    k1_kernel<<<NB1, 256, 0, stream>>>(feat, ei, featbf, out, cnt1);
    k2_kernel<<<1, 512, 0, stream>>>(cnt1, base, ticket);
    k3_kernel<<<2048, 256, 0, stream>>>(ei, ea, ticket, rec);
    p2_kernel<<<NB1, 512, 0, stream>>>(base, rec);
    edge_mfma_kernel<<<GRID, 256, 0, stream>>>(featbf, pos, W, b, rec, out);
    finalize_kernel<<<2048, 256, 0, stream>>>((float*)out, NNODES * COUT);
}